// Round 6
// baseline (726.427 us; speedup 1.0000x reference)
//
#include <hip/hip_runtime.h>

#define S_LEN 2048
#define DMODEL 4096
#define NQKV 6144   // 32*128 + 8*128 + 8*128

typedef unsigned short u16;
typedef __attribute__((ext_vector_type(8))) short bf16x8;
typedef __attribute__((ext_vector_type(8))) unsigned short u16x8;
typedef __attribute__((ext_vector_type(4))) float f32x4;

#define NEG_BIG (-3.0e38f)

__device__ __forceinline__ float bf2f(u16 h) {
    union { unsigned u; float f; } c; c.u = ((unsigned)h) << 16; return c.f;
}
__device__ __forceinline__ u16 f2bf(float x) {
    union { float f; unsigned u; } c; c.f = x;
    return (u16)((c.u + 0x7fffu + ((c.u >> 16) & 1u)) >> 16);
}

// ------------- dtype probe: flag[0]=1 if `probe` is fp32-underlying ------------
__global__ __launch_bounds__(256) void detect_dtype(const u16* __restrict__ probe,
                                                    int* __restrict__ flags) {
    __shared__ int bad_s;
    if (threadIdx.x == 0) bad_s = 0;
    __syncthreads();
    int bad = 0;
    for (int i = threadIdx.x; i < 16384; i += 256) {
        float v = bf2f(probe[i]);
        if (!(fabsf(v) < 1e6f)) bad = 1;   // catches NaN too
    }
    if (bad) atomicOr(&bad_s, 1);
    __syncthreads();
    if (threadIdx.x == 0) { flags[0] = bad_s; flags[1] = 0; }
}

// ------------- convert (fp32 or bf16) -> bf16, flat ----------------------------
__global__ __launch_bounds__(256) void conv_bf16(const void* __restrict__ src,
                                                 u16* __restrict__ dst, long n,
                                                 const int* __restrict__ flag) {
    const bool f32 = (*flag != 0);
    long i = (long)blockIdx.x * 256 + threadIdx.x;
    long stride = (long)gridDim.x * 256;
    for (; i < n; i += stride) {
        float v = f32 ? ((const float*)src)[i] : bf2f(((const u16*)src)[i]);
        dst[i] = f2bf(v);
    }
}

// ------------- transpose (fp32-or-bf16 in, bf16 out): dst[c][r] = src[r][c] ----
__global__ __launch_bounds__(256) void transpose_any(
        const void* __restrict__ src, long base_off, long sld, long szoff,
        u16* __restrict__ dst, long dld, long dzoff,
        const int* __restrict__ flag) {
    __shared__ alignas(16) u16 tile[32][33];
    const bool f32 = (*flag != 0);
    u16* d = dst + (long)blockIdx.z * dzoff;
    long soff = base_off + (long)blockIdx.z * szoff;
    int c0 = blockIdx.x * 32, r0 = blockIdx.y * 32;
    int tx = threadIdx.x & 31, ty = threadIdx.x >> 5;   // 32x8
    for (int i = 0; i < 32; i += 8) {
        long idx = soff + (long)(r0 + ty + i) * sld + c0 + tx;
        float v = f32 ? ((const float*)src)[idx] : bf2f(((const u16*)src)[idx]);
        tile[ty + i][tx] = f2bf(v);
    }
    __syncthreads();
    for (int i = 0; i < 32; i += 8)
        d[(long)(c0 + ty + i) * dld + r0 + tx] = tile[tx][ty + i];
}

// ---------------- GEMM: C[m][n] = sum_k A[m][k] * BT[n][k], bf16 in/out --------
__global__ __launch_bounds__(256, 2) void gemm_bt(
        const u16* __restrict__ A, const u16* __restrict__ BT,
        u16* __restrict__ C, int K, int ldc) {
    __shared__ alignas(16) u16 Asm[128 * 64];
    __shared__ alignas(16) u16 Bsm[128 * 64];
    const int tid = threadIdx.x;
    const int lane = tid & 63, wid = tid >> 6;
    const int wm = wid >> 1, wn = wid & 1;           // 2x2 waves, 64x64 each
    const int lm = lane & 15, lq = lane >> 4;
    const int m0 = blockIdx.y * 128, n0 = blockIdx.x * 128;

    f32x4 acc[4][4] = {};
    const int nk = K >> 6;
    for (int kt = 0; kt < nk; ++kt) {
        const int k0 = kt << 6;
        u16x8 areg[4], breg[4];
        for (int i = 0; i < 4; ++i) {
            int g = i * 256 + tid;
            int r = g >> 3, kg = g & 7;
            areg[i] = *(const u16x8*)(const void*)(A  + (size_t)(m0 + r) * K + k0 + kg * 8);
            breg[i] = *(const u16x8*)(const void*)(BT + (size_t)(n0 + r) * K + k0 + kg * 8);
        }
        __syncthreads();
        for (int i = 0; i < 4; ++i) {
            int g = i * 256 + tid;
            *(u16x8*)(void*)(Asm + (size_t)g * 8) = areg[i];
            *(u16x8*)(void*)(Bsm + (size_t)g * 8) = breg[i];
        }
        __syncthreads();
        for (int ks = 0; ks < 2; ++ks) {
            bf16x8 af[4], bfr[4];
            for (int i = 0; i < 4; ++i)
                af[i] = *(const bf16x8*)(const void*)(Asm + (wm * 64 + i * 16 + lm) * 64 + ks * 32 + lq * 8);
            for (int i = 0; i < 4; ++i)
                bfr[i] = *(const bf16x8*)(const void*)(Bsm + (wn * 64 + i * 16 + lm) * 64 + ks * 32 + lq * 8);
            for (int mi = 0; mi < 4; ++mi)
                for (int ni = 0; ni < 4; ++ni)
                    acc[mi][ni] = __builtin_amdgcn_mfma_f32_16x16x32_bf16(af[mi], bfr[ni], acc[mi][ni], 0, 0, 0);
        }
    }
    for (int mi = 0; mi < 4; ++mi)
        for (int ni = 0; ni < 4; ++ni) {
            int col = n0 + wn * 64 + ni * 16 + lm;
            int rowb = m0 + wm * 64 + mi * 16 + lq * 4;
            for (int r = 0; r < 4; ++r)
                C[(size_t)(rowb + r) * ldc + col] = f2bf(acc[mi][ni][r]);
        }
}

// ---------------- same GEMM, fp32 output (for d_out) ---------------------------
__global__ __launch_bounds__(256, 2) void gemm_bt_f32(
        const u16* __restrict__ A, const u16* __restrict__ BT,
        float* __restrict__ C, int K, int ldc) {
    __shared__ alignas(16) u16 Asm[128 * 64];
    __shared__ alignas(16) u16 Bsm[128 * 64];
    const int tid = threadIdx.x;
    const int lane = tid & 63, wid = tid >> 6;
    const int wm = wid >> 1, wn = wid & 1;
    const int lm = lane & 15, lq = lane >> 4;
    const int m0 = blockIdx.y * 128, n0 = blockIdx.x * 128;

    f32x4 acc[4][4] = {};
    const int nk = K >> 6;
    for (int kt = 0; kt < nk; ++kt) {
        const int k0 = kt << 6;
        u16x8 areg[4], breg[4];
        for (int i = 0; i < 4; ++i) {
            int g = i * 256 + tid;
            int r = g >> 3, kg = g & 7;
            areg[i] = *(const u16x8*)(const void*)(A  + (size_t)(m0 + r) * K + k0 + kg * 8);
            breg[i] = *(const u16x8*)(const void*)(BT + (size_t)(n0 + r) * K + k0 + kg * 8);
        }
        __syncthreads();
        for (int i = 0; i < 4; ++i) {
            int g = i * 256 + tid;
            *(u16x8*)(void*)(Asm + (size_t)g * 8) = areg[i];
            *(u16x8*)(void*)(Bsm + (size_t)g * 8) = breg[i];
        }
        __syncthreads();
        for (int ks = 0; ks < 2; ++ks) {
            bf16x8 af[4], bfr[4];
            for (int i = 0; i < 4; ++i)
                af[i] = *(const bf16x8*)(const void*)(Asm + (wm * 64 + i * 16 + lm) * 64 + ks * 32 + lq * 8);
            for (int i = 0; i < 4; ++i)
                bfr[i] = *(const bf16x8*)(const void*)(Bsm + (wn * 64 + i * 16 + lm) * 64 + ks * 32 + lq * 8);
            for (int mi = 0; mi < 4; ++mi)
                for (int ni = 0; ni < 4; ++ni)
                    acc[mi][ni] = __builtin_amdgcn_mfma_f32_16x16x32_bf16(af[mi], bfr[ni], acc[mi][ni], 0, 0, 0);
        }
    }
    for (int mi = 0; mi < 4; ++mi)
        for (int ni = 0; ni < 4; ++ni) {
            int col = n0 + wn * 64 + ni * 16 + lm;
            int rowb = m0 + wm * 64 + mi * 16 + lq * 4;
            for (int r = 0; r < 4; ++r)
                C[(size_t)(rowb + r) * ldc + col] = acc[mi][ni][r];   // fp32 out
        }
}

// ---------------- RMSNorm + RoPE on q (32 heads) and k (8 heads) ---------------
__global__ __launch_bounds__(256) void rms_rope(
        const u16* __restrict__ qkv, const int* __restrict__ pos,
        const u16* __restrict__ qs, const u16* __restrict__ kscale,
        u16* __restrict__ Qb, u16* __restrict__ Kb) {
    int w = threadIdx.x >> 6, lane = threadIdx.x & 63;
    int task = blockIdx.x * 4 + w;            // task = h*2048 + row, h in [0,40)
    int h = task >> 11, row = task & 2047;
    int base = (h < 32) ? h * 128 : 4096 + (h - 32) * 128;
    const u16* src = qkv + (size_t)row * NQKV + base;
    float t0 = bf2f(src[lane]), t1 = bf2f(src[lane + 64]);
    float ss = t0 * t0 + t1 * t1;
    for (int m = 1; m < 64; m <<= 1) ss += __shfl_xor(ss, m);
    float inv = rsqrtf(ss * (1.0f / 128.0f) + 1e-6f);
    const u16* sc = (h < 32) ? qs : kscale;
    float n0 = t0 * inv * bf2f(sc[lane]);
    float n1 = t1 * inv * bf2f(sc[lane + 64]);
    float p = (float)pos[row];
    float ang = p * __expf(-(float)lane * (9.210340371976184f / 64.0f));  // 10000^(-lane/64)
    float c = cosf(ang), s = sinf(ang);
    float o0 = n0 * c - n1 * s;
    float o1 = n1 * c + n0 * s;
    u16* dst = (h < 32) ? (Qb + ((size_t)h * S_LEN + row) * 128)
                        : (Kb + ((size_t)(h - 32) * S_LEN + row) * 128);
    dst[lane] = f2bf(o0);
    dst[lane + 64] = f2bf(o1);
}

// ---------------- flash attention: 128-row Q tile, 64-row KV tiles -------------
// (certified equal to the VALU reference by the round-4/5 bisect)
__global__ __launch_bounds__(256, 2) void flash_attn(
        const u16* __restrict__ Qb, const u16* __restrict__ Kb,
        const u16* __restrict__ VTb, u16* __restrict__ ctx) {
    const int t = blockIdx.x, h = blockIdx.y, kvh = h >> 2;
    const int tid = threadIdx.x, lane = tid & 63, w = tid >> 6;
    const int lm = lane & 15, lq = lane >> 4;
    __shared__ alignas(16) u16 smem[24576];   // 48 KB
    u16* Ksm = smem;                     // [64][128]
    u16* Vsm = smem + 8192;              // VT tile [d=128][n=64]
    u16* Psm = smem + 16384;             // [m=128][n=64]
    const u16* Qh = Qb + ((size_t)h * S_LEN + (size_t)t * 128) * 128;
    const u16* Kh = Kb + (size_t)kvh * S_LEN * 128;
    const u16* Vh = VTb + (size_t)kvh * 128 * S_LEN;

    for (int i = 0; i < 8; ++i) {
        int g = i * 256 + tid;
        *(u16x8*)(void*)(smem + (size_t)g * 8) = *(const u16x8*)(const void*)(Qh + (size_t)g * 8);
    }
    __syncthreads();
    bf16x8 aq[2][4];
    for (int mi = 0; mi < 2; ++mi)
        for (int ks = 0; ks < 4; ++ks)
            aq[mi][ks] = *(const bf16x8*)(const void*)(smem + (w * 32 + mi * 16 + lm) * 128 + ks * 32 + lq * 8);

    float mrow[2][4], lrow[2][4];
    f32x4 accO[2][8];
    const f32x4 zero = {0.f, 0.f, 0.f, 0.f};
    for (int mi = 0; mi < 2; ++mi)
        for (int r = 0; r < 4; ++r) { mrow[mi][r] = NEG_BIG; lrow[mi][r] = 0.f; }
    for (int mi = 0; mi < 2; ++mi)
        for (int di = 0; di < 8; ++di) accO[mi][di] = zero;

    const float SC = 0.08838834764831845f;   // 1/sqrt(128)
    const int jmax = 2 * t + 1;
    for (int j = 0; j <= jmax; ++j) {
        __syncthreads();
        for (int i = 0; i < 4; ++i) {
            int g = i * 256 + tid;
            *(u16x8*)(void*)(Ksm + (size_t)g * 8) =
                *(const u16x8*)(const void*)(Kh + (size_t)(j * 64) * 128 + (size_t)g * 8);
        }
        for (int i = 0; i < 4; ++i) {
            int g = i * 256 + tid;
            int d = g >> 3, kg = g & 7;
            *(u16x8*)(void*)(Vsm + (size_t)g * 8) =
                *(const u16x8*)(const void*)(Vh + (size_t)d * S_LEN + j * 64 + kg * 8);
        }
        __syncthreads();

        f32x4 sacc[2][4] = {};
        for (int ks = 0; ks < 4; ++ks) {
            bf16x8 kf[4];
            for (int ni = 0; ni < 4; ++ni)
                kf[ni] = *(const bf16x8*)(const void*)(Ksm + (ni * 16 + lm) * 128 + ks * 32 + lq * 8);
            for (int mi = 0; mi < 2; ++mi)
                for (int ni = 0; ni < 4; ++ni)
                    sacc[mi][ni] = __builtin_amdgcn_mfma_f32_16x16x32_bf16(aq[mi][ks], kf[ni], sacc[mi][ni], 0, 0, 0);
        }

        for (int mi = 0; mi < 2; ++mi) {
            int rbase = t * 128 + w * 32 + mi * 16 + lq * 4;
            for (int ni = 0; ni < 4; ++ni) {
                int colg = j * 64 + ni * 16 + lm;
                for (int r = 0; r < 4; ++r) {
                    float sv = sacc[mi][ni][r] * SC;
                    sacc[mi][ni][r] = (colg > rbase + r) ? NEG_BIG : sv;
                }
            }
            for (int r = 0; r < 4; ++r) {
                float mx = fmaxf(fmaxf(sacc[mi][0][r], sacc[mi][1][r]),
                                 fmaxf(sacc[mi][2][r], sacc[mi][3][r]));
                for (int sft = 1; sft < 16; sft <<= 1) mx = fmaxf(mx, __shfl_xor(mx, sft));
                float mN = fmaxf(mrow[mi][r], mx);
                float alpha = __expf(mrow[mi][r] - mN);
                mrow[mi][r] = mN;
                float psum = 0.f;
                for (int ni = 0; ni < 4; ++ni) {
                    float d = sacc[mi][ni][r] - mN;
                    float pv = __expf(d);
                    psum += pv;
                    Psm[(w * 32 + mi * 16 + lq * 4 + r) * 64 + ni * 16 + lm] = f2bf(pv);
                }
                for (int sft = 1; sft < 16; sft <<= 1) psum += __shfl_xor(psum, sft);
                lrow[mi][r] = lrow[mi][r] * alpha + psum;
                for (int di = 0; di < 8; ++di) accO[mi][di][r] *= alpha;
            }
        }
        __syncthreads();

        for (int ks2 = 0; ks2 < 2; ++ks2) {
            bf16x8 pf[2];
            for (int mi = 0; mi < 2; ++mi)
                pf[mi] = *(const bf16x8*)(const void*)(Psm + (w * 32 + mi * 16 + lm) * 64 + ks2 * 32 + lq * 8);
            for (int di = 0; di < 8; ++di) {
                bf16x8 vf = *(const bf16x8*)(const void*)(Vsm + (di * 16 + lm) * 64 + ks2 * 32 + lq * 8);
                for (int mi = 0; mi < 2; ++mi)
                    accO[mi][di] = __builtin_amdgcn_mfma_f32_16x16x32_bf16(pf[mi], vf, accO[mi][di], 0, 0, 0);
            }
        }
    }

    for (int mi = 0; mi < 2; ++mi)
        for (int r = 0; r < 4; ++r) {
            float invl = 1.0f / fmaxf(lrow[mi][r], 1e-30f);
            int rowg = t * 128 + w * 32 + mi * 16 + lq * 4 + r;
            for (int di = 0; di < 8; ++di)
                ctx[(size_t)rowg * 4096 + h * 128 + di * 16 + lm] = f2bf(accO[mi][di][r] * invl);
        }
}

extern "C" void kernel_launch(void* const* d_in, const int* in_sizes, int n_in,
                              void* d_out, int out_size, void* d_ws, size_t ws_size,
                              hipStream_t stream) {
    const void* x   = d_in[0];
    const int* pos  = (const int*)d_in[1];
    const void* Wq  = d_in[2];
    const void* Wk  = d_in[3];
    const void* Wv  = d_in[4];
    const void* Wo  = d_in[5];
    const void* qs  = d_in[6];
    const void* ks  = d_in[7];

    if (ws_size < (size_t)145 * 1024 * 1024) return;
    char* ws = (char*)d_ws;
    u16* WqkvT = (u16*)ws;                                  // [6144][4096]   48 MiB
    u16* WoT   = (u16*)(ws + (size_t)48  * 1024 * 1024);    // [4096][4096]   32 MiB
    u16* qkv   = (u16*)(ws + (size_t)80  * 1024 * 1024);    // [2048][6144]   24 MiB
    u16* ctx   = qkv;                                       // aliases qkv (dead after VT/rms)
    u16* Qb    = (u16*)(ws + (size_t)104 * 1024 * 1024);    // [32][2048][128] 16 MiB
    u16* Kb    = (u16*)(ws + (size_t)120 * 1024 * 1024);    // [8][2048][128]   4 MiB
    u16* VTb   = (u16*)(ws + (size_t)124 * 1024 * 1024);    // [8][128][2048]   4 MiB
    u16* xb    = (u16*)(ws + (size_t)128 * 1024 * 1024);    // [2048][4096]    16 MiB
    int* flags = (int*)(ws + (size_t)144 * 1024 * 1024);
    u16* qsb   = (u16*)(ws + (size_t)144 * 1024 * 1024 + 1024);
    u16* ksb   = (u16*)(ws + (size_t)144 * 1024 * 1024 + 2048);

    dim3 b256(256);
    const int* flag  = flags;       // probed dtype
    const int* fzero = flags + 1;   // always 0

    detect_dtype<<<1, b256, 0, stream>>>((const u16*)Wq, flags);
    conv_bf16<<<8192, b256, 0, stream>>>(x,  xb,  (long)S_LEN * DMODEL, flag);
    conv_bf16<<<1,    b256, 0, stream>>>(qs, qsb, 128, flag);
    conv_bf16<<<1,    b256, 0, stream>>>(ks, ksb, 128, flag);

    // weight transposes into k-contiguous B^T layouts (bf16 out)
    transpose_any<<<dim3(128, 128, 1), b256, 0, stream>>>(Wq, 0, 4096, 0, WqkvT, 4096, 0, flag);
    transpose_any<<<dim3(32, 128, 1),  b256, 0, stream>>>(Wk, 0, 1024, 0, WqkvT + (size_t)4096 * 4096, 4096, 0, flag);
    transpose_any<<<dim3(32, 128, 1),  b256, 0, stream>>>(Wv, 0, 1024, 0, WqkvT + (size_t)5120 * 4096, 4096, 0, flag);
    transpose_any<<<dim3(128, 128, 1), b256, 0, stream>>>(Wo, 0, 4096, 0, WoT, 4096, 0, flag);

    // fused QKV projection: [2048][6144] bf16
    gemm_bt<<<dim3(48, 16), b256, 0, stream>>>(xb, WqkvT, qkv, 4096, NQKV);
    // RMSNorm + RoPE -> head-major Q/K
    rms_rope<<<dim3(20480), b256, 0, stream>>>(qkv, pos, qsb, ksb, Qb, Kb);
    // V -> V^T per kv head ([8][128][2048]); qkv is bf16 -> force bf16 path
    transpose_any<<<dim3(4, 64, 8), b256, 0, stream>>>(qkv, 5120, NQKV, 128, VTb, 2048, (long)128 * 2048, fzero);
    // causal GQA flash attention -> ctx [2048][4096]
    flash_attn<<<dim3(16, 32), b256, 0, stream>>>(Qb, Kb, VTb, ctx);
    // output projection -> d_out as FP32 (reference output dtype is float32)
    gemm_bt_f32<<<dim3(32, 16), b256, 0, stream>>>(ctx, WoT, (float*)d_out, 4096, 4096);
}